// Round 6
// baseline (136.207 us; speedup 1.0000x reference)
//
#include <hip/hip_runtime.h>
#include <hip/hip_bf16.h>

#define NB 16
#define SS 2048
#define DD 64

typedef __attribute__((ext_vector_type(8))) short short8;
typedef __attribute__((ext_vector_type(4))) float f32x4;

// SCALE * log2(e), folded so softmax exp is one v_mul + one v_exp
#define SCL2E 0.18033688011112042f

// partial slot: 32x64 acc + 32 l, padded
#define PSLOT 2080

// round-to-nearest-even f32 -> bf16 (as raw short)
__device__ __forceinline__ short f2bf(float f) {
  union { float f; unsigned u; } v; v.f = f;
  unsigned r = (v.u + 0x7fffu + ((v.u >> 16) & 1u)) >> 16;
  return (short)r;
}

__device__ __forceinline__ short8 load_a_frag_f32(const float* p) {
  float4 u = *(const float4*)p;
  float4 w = *(const float4*)(p + 4);
  short8 r;
  r[0] = f2bf(u.x); r[1] = f2bf(u.y); r[2] = f2bf(u.z); r[3] = f2bf(u.w);
  r[4] = f2bf(w.x); r[5] = f2bf(w.y); r[6] = f2bf(w.z); r[7] = f2bf(w.w);
  return r;
}

// ---------------------------------------------------------------------------
// QKV projection. Block = 4 waves = 64 seq rows. W bf16->LDS once per block.
// Q,K: MFMA C/D -> LDS tile -> COALESCED row-major 16B stores (was 2B scatter).
// V: LDS transpose -> vT[b][d][s].
// ---------------------------------------------------------------------------
__global__ __launch_bounds__(256) void proj_kernel(
    const float* __restrict__ x,
    const float* __restrict__ Wq, const float* __restrict__ bq,
    const float* __restrict__ Wk, const float* __restrict__ bk,
    const float* __restrict__ Wv, const float* __restrict__ bv,
    ushort* __restrict__ qo, ushort* __restrict__ ko, ushort* __restrict__ vT)
{
  __shared__ __align__(16) ushort Wt[3][64][72];   // W^T[n][k], bf16
  __shared__ __align__(16) ushort Vs[64][72];      // staging tile (72: 16B rows)
  const int t = threadIdx.x;
  {
    const float* Ws[3] = {Wq, Wk, Wv};
    for (int m = 0; m < 3; ++m)
      for (int i = 0; i < 4; ++i) {
        int idx = i * 1024 + t * 4;
        int kk = idx >> 6, n0 = idx & 63;
        float4 w4 = *(const float4*)(Ws[m] + kk * 64 + n0);
        Wt[m][n0 + 0][kk] = (ushort)f2bf(w4.x);
        Wt[m][n0 + 1][kk] = (ushort)f2bf(w4.y);
        Wt[m][n0 + 2][kk] = (ushort)f2bf(w4.z);
        Wt[m][n0 + 3][kk] = (ushort)f2bf(w4.w);
      }
  }
  __syncthreads();

  const int lane = t & 63, w = t >> 6;
  const int l15 = lane & 15, quad = lane >> 4;
  const int g = blockIdx.x * 64 + w * 16 + l15;
  short8 a0 = load_a_frag_f32(x + (size_t)g * 64 + quad * 8);
  short8 a1 = load_a_frag_f32(x + (size_t)g * 64 + 32 + quad * 8);
  const int lrow0 = w * 16 + quad * 4;

  for (int m = 0; m < 3; ++m) {
    const float* bp = (m == 0 ? bq : (m == 1 ? bk : bv));
#pragma unroll
    for (int nt = 0; nt < 4; ++nt) {
      short8 b0 = *(const short8*)&Wt[m][nt * 16 + l15][quad * 8];
      short8 b1 = *(const short8*)&Wt[m][nt * 16 + l15][32 + quad * 8];
      f32x4 acc = {0.f, 0.f, 0.f, 0.f};
      acc = __builtin_amdgcn_mfma_f32_16x16x32_bf16(a0, b0, acc, 0, 0, 0);
      acc = __builtin_amdgcn_mfma_f32_16x16x32_bf16(a1, b1, acc, 0, 0, 0);
      float bb = bp[nt * 16 + l15];
#pragma unroll
      for (int r = 0; r < 4; ++r)
        Vs[lrow0 + r][nt * 16 + l15] = (ushort)f2bf(acc[r] + bb);
    }
    __syncthreads();
    if (m < 2) {
      // coalesced row-major store: thread -> 32 B of one row
      ushort* outp = (m == 0 ? qo : ko);
      const int row = t >> 2, col0 = (t & 3) * 16;
      int4 d0 = *(const int4*)&Vs[row][col0];
      int4 d1 = *(const int4*)&Vs[row][col0 + 8];
      ushort* dst = outp + (size_t)(blockIdx.x * 64 + row) * 64 + col0;
      ((int4*)dst)[0] = d0;
      ((int4*)dst)[1] = d1;
    } else {
      // V transpose: vT[b][d][s0..s0+63]
      const int batch = blockIdx.x >> 5;
      const int s0 = (blockIdx.x & 31) * 64;
      const int d = t >> 2, j0 = (t & 3) * 16;
      ushort tmp[16];
      for (int j = 0; j < 16; ++j) tmp[j] = Vs[j0 + j][d];
      ushort* dst = vT + (size_t)batch * DD * SS + (size_t)d * SS + s0 + j0;
      ((int4*)dst)[0] = ((int4*)tmp)[0];
      ((int4*)dst)[1] = ((int4*)tmp)[1];
    }
    if (m < 2) __syncthreads();   // Vs reused next m
  }
}

// ---------------------------------------------------------------------------
// exp + packed P write + PV for one 16-query half. Key interleave: c[ct] at
// lane l15 is key kb + 4*l15 + ct -> lane's 4 P-values are adjacent cols ->
// 2x v_cvt_pk_bf16_f32 + one ds_write_b64 per row. MASKED compile-time.
// ---------------------------------------------------------------------------
template<bool MASKED>
__device__ __forceinline__ void attn_half(
    const f32x4 (&c)[4], float (&l_part)[4], f32x4 (&acc)[4],
    const short8 (&vf0)[4], const short8 (&vf1)[4],
    ushort* __restrict__ Pw, int kb4, int rowb, int l15, int quad)
{
#pragma unroll
  for (int r = 0; r < 4; ++r) {
    float pe[4];
#pragma unroll
    for (int ct = 0; ct < 4; ++ct) {
      pe[ct] = __builtin_amdgcn_exp2f(c[ct][r] * SCL2E);
      if (MASKED && (kb4 + ct > rowb + r)) pe[ct] = 0.f;
    }
    l_part[r] += (pe[0] + pe[1]) + (pe[2] + pe[3]);
    __hip_bfloat162 h01 = __float22bfloat162_rn(make_float2(pe[0], pe[1]));
    __hip_bfloat162 h23 = __float22bfloat162_rn(make_float2(pe[2], pe[3]));
    uint2 pwv;
    pwv.x = *reinterpret_cast<unsigned*>(&h01);
    pwv.y = *reinterpret_cast<unsigned*>(&h23);
    *(uint2*)&Pw[(quad * 4 + r) * 72 + 4 * l15] = pwv;
  }
  short8 pa0 = *(const short8*)&Pw[l15 * 72 + quad * 8];
  short8 pa1 = *(const short8*)&Pw[l15 * 72 + 32 + quad * 8];
#pragma unroll
  for (int nt = 0; nt < 4; ++nt) {
    acc[nt] = __builtin_amdgcn_mfma_f32_16x16x32_bf16(pa0, vf0[nt], acc[nt], 0, 0, 0);
    acc[nt] = __builtin_amdgcn_mfma_f32_16x16x32_bf16(pa1, vf1[nt], acc[nt], 0, 0, 0);
  }
}

// ---------------------------------------------------------------------------
// Equal-work chunked flash attention. Block = (batch, 32-query tile, 512-key
// chunk): uniform ~2 tile-iters/wave -> sustained occupancy, no causal tail.
// No-max softmax => partials are plain sums; block writes unnormalized
// 32x64 partial + 32 row-sums; combine kernel finishes.
// ---------------------------------------------------------------------------
__global__ __launch_bounds__(256, 2) void attn_part(
    const ushort* __restrict__ qg, const ushort* __restrict__ kg,
    const ushort* __restrict__ vT, float* __restrict__ pws)
{
  // union: wave-private P buffers (9216 B) overlay accW (34816 B)
  __shared__ __align__(16) float accW[4][32][68];
  __shared__ float lW[4][32];
  ushort* Pw_base = (ushort*)&accW[0][0][0];

  const int t = threadIdx.x, bid = blockIdx.x;
  const int batch = (bid & 7) * 2 + ((bid >> 3) & 1);  // spread batches on XCDs
  const int local = bid >> 4;                          // 0..159
  int qt, c;
  if (local < 16)      { qt = local;                 c = 0; }
  else if (local < 48) { int u = local - 16; qt = 16 + (u >> 1); c = u & 1; }
  else if (local < 96) { int u = local - 48; int q3 = u / 3; qt = 32 + q3; c = u - 3 * q3; }
  else                 { int u = local - 96; qt = 48 + (u >> 2); c = u & 3; }

  const int q0 = qt * 32;
  const int nkt = (qt >> 1) + 1;                 // total 64-key tiles for qt
  const int tend = min(8 * c + 8, nkt);          // this chunk's tile bound
  const int lane = t & 63, w = t >> 6;
  const int l15 = lane & 15, quad = lane >> 4;
  const size_t bbase = (size_t)batch * SS * DD;
  ushort* Pw = Pw_base + w * (16 * 72);

  // A-frags for both q-halves
  const ushort* qp = qg + bbase + (size_t)(q0 + l15) * 64 + quad * 8;
  short8 a0 = *(const short8*)qp;
  short8 a1 = *(const short8*)(qp + 32);
  short8 a2 = *(const short8*)(qp + 16 * 64);
  short8 a3 = *(const short8*)(qp + 16 * 64 + 32);

  f32x4 acc0[4], acc1[4];
  float l0[4] = {0.f, 0.f, 0.f, 0.f}, l1[4] = {0.f, 0.f, 0.f, 0.f};
#pragma unroll
  for (int nt = 0; nt < 4; ++nt) {
    acc0[nt] = (f32x4){0.f, 0.f, 0.f, 0.f};
    acc1[nt] = (f32x4){0.f, 0.f, 0.f, 0.f};
  }

  // K base with key interleave: frag ct, lane l15 -> key 4*l15 + ct
  const int t0 = 8 * c + w;                      // this wave's first tile
  const ushort* kpc = kg + bbase + (size_t)(4 * l15) * 64 + quad * 8
                    + (size_t)t0 * 4096;
  const ushort* vp0 = vT + bbase + (size_t)l15 * SS + t0 * 64 + quad * 8;
  const ushort* vp1 = vp0 + 16 * SS;
  const ushort* vp2 = vp0 + 32 * SS;
  const ushort* vp3 = vp0 + 48 * SS;

  // pre-load first K tile (tile index <= 27 -> always in-bounds; unused if 0 iters)
  short8 kc0[4], kc1[4];
#pragma unroll
  for (int ct = 0; ct < 4; ++ct) {
    kc0[ct] = *(const short8*)(kpc + ct * 64);
    kc1[ct] = *(const short8*)(kpc + ct * 64 + 32);
  }

  for (int kt = t0; kt < tend; kt += 4) {
    short8 vf0[4], vf1[4];
    vf0[0] = *(const short8*)(vp0); vf1[0] = *(const short8*)(vp0 + 32);
    vf0[1] = *(const short8*)(vp1); vf1[1] = *(const short8*)(vp1 + 32);
    vf0[2] = *(const short8*)(vp2); vf1[2] = *(const short8*)(vp2 + 32);
    vf0[3] = *(const short8*)(vp3); vf1[3] = *(const short8*)(vp3 + 32);

    const ushort* kpn = (kt + 4 < tend) ? (kpc + 16384) : kpc;
    short8 kn0[4], kn1[4];
#pragma unroll
    for (int ct = 0; ct < 4; ++ct) {
      kn0[ct] = *(const short8*)(kpn + ct * 64);
      kn1[ct] = *(const short8*)(kpn + ct * 64 + 32);
    }

    f32x4 c0[4], c1[4];
#pragma unroll
    for (int ct = 0; ct < 4; ++ct) {
      c0[ct] = (f32x4){0.f, 0.f, 0.f, 0.f};
      c0[ct] = __builtin_amdgcn_mfma_f32_16x16x32_bf16(a0, kc0[ct], c0[ct], 0, 0, 0);
      c0[ct] = __builtin_amdgcn_mfma_f32_16x16x32_bf16(a1, kc1[ct], c0[ct], 0, 0, 0);
      c1[ct] = (f32x4){0.f, 0.f, 0.f, 0.f};
      c1[ct] = __builtin_amdgcn_mfma_f32_16x16x32_bf16(a2, kc0[ct], c1[ct], 0, 0, 0);
      c1[ct] = __builtin_amdgcn_mfma_f32_16x16x32_bf16(a3, kc1[ct], c1[ct], 0, 0, 0);
    }

    const int kb4 = kt * 64 + 4 * l15;
    if (kt == nkt - 1) {
      attn_half<true >(c0, l0, acc0, vf0, vf1, Pw, kb4, q0 + quad * 4, l15, quad);
      attn_half<true >(c1, l1, acc1, vf0, vf1, Pw, kb4, q0 + 16 + quad * 4, l15, quad);
    } else {
      attn_half<false>(c0, l0, acc0, vf0, vf1, Pw, kb4, q0 + quad * 4, l15, quad);
      attn_half<false>(c1, l1, acc1, vf0, vf1, Pw, kb4, q0 + 16 + quad * 4, l15, quad);
    }

#pragma unroll
    for (int ct = 0; ct < 4; ++ct) { kc0[ct] = kn0[ct]; kc1[ct] = kn1[ct]; }
    kpc = kpn;
    vp0 += 256; vp1 += 256; vp2 += 256; vp3 += 256;
  }

  // l reduce over 16-lane row groups
#pragma unroll
  for (int r = 0; r < 4; ++r)
    for (int off = 1; off < 16; off <<= 1) {
      l0[r] += __shfl_xor(l0[r], off, 64);
      l1[r] += __shfl_xor(l1[r], off, 64);
    }

  __syncthreads();   // all waves done with P region before accW overlay
#pragma unroll
  for (int r = 0; r < 4; ++r)
#pragma unroll
    for (int nt = 0; nt < 4; ++nt) {
      accW[w][quad * 4 + r][nt * 16 + l15] = acc0[nt][r];
      accW[w][16 + quad * 4 + r][nt * 16 + l15] = acc1[nt][r];
    }
  if (l15 == 0)
#pragma unroll
    for (int r = 0; r < 4; ++r) {
      lW[w][quad * 4 + r] = l0[r];
      lW[w][16 + quad * 4 + r] = l1[r];
    }
  __syncthreads();

  // write unnormalized partial (plain sums)
  {
    const int row = t >> 3, col0 = (t & 7) * 8;
    float* ps = pws + (size_t)(((batch << 6) + qt) * 4 + c) * PSLOT;
    float4 oa = {0.f, 0.f, 0.f, 0.f}, ob = {0.f, 0.f, 0.f, 0.f};
#pragma unroll
    for (int ww = 0; ww < 4; ++ww) {
      float4 x0 = *(const float4*)&accW[ww][row][col0];
      float4 x1 = *(const float4*)&accW[ww][row][col0 + 4];
      oa.x += x0.x; oa.y += x0.y; oa.z += x0.z; oa.w += x0.w;
      ob.x += x1.x; ob.y += x1.y; ob.z += x1.z; ob.w += x1.w;
    }
    *(float4*)(ps + row * 64 + col0) = oa;
    *(float4*)(ps + row * 64 + col0 + 4) = ob;
    if ((t & 7) == 0)
      ps[2048 + row] = lW[0][row] + lW[1][row] + lW[2][row] + lW[3][row];
  }
}

// ---------------------------------------------------------------------------
// Combine: block = (batch, qt). Sum <=4 partials, normalize, store fp32 out.
// ---------------------------------------------------------------------------
__global__ __launch_bounds__(256) void combine_kernel(
    const float* __restrict__ pws, float* __restrict__ out)
{
  __shared__ float inv_s[32];
  const int t = threadIdx.x, bid = blockIdx.x;
  const int batch = bid >> 6, qt = bid & 63;
  const int q0 = qt * 32;
  const int nch = (qt >> 4) + 1;
  const float* ps0 = pws + (size_t)(((batch << 6) + qt) * 4) * PSLOT;

  if (t < 32) {
    float d = 0.f;
    for (int c = 0; c < nch; ++c) d += ps0[c * PSLOT + 2048 + t];
    inv_s[t] = 1.0f / d;
  }
  __syncthreads();

  const int row = t >> 3, col0 = (t & 7) * 8;
  float4 oa = {0.f, 0.f, 0.f, 0.f}, ob = {0.f, 0.f, 0.f, 0.f};
  for (int c = 0; c < nch; ++c) {
    float4 x0 = *(const float4*)(ps0 + c * PSLOT + row * 64 + col0);
    float4 x1 = *(const float4*)(ps0 + c * PSLOT + row * 64 + col0 + 4);
    oa.x += x0.x; oa.y += x0.y; oa.z += x0.z; oa.w += x0.w;
    ob.x += x1.x; ob.y += x1.y; ob.z += x1.z; ob.w += x1.w;
  }
  float iv = inv_s[row];
  oa.x *= iv; oa.y *= iv; oa.z *= iv; oa.w *= iv;
  ob.x *= iv; ob.y *= iv; ob.z *= iv; ob.w *= iv;
  float* op = out + (size_t)batch * SS * DD + (size_t)(q0 + row) * 64 + col0;
  *(float4*)op = oa;
  *(float4*)(op + 4) = ob;
}

extern "C" void kernel_launch(void* const* d_in, const int* in_sizes, int n_in,
                              void* d_out, int out_size, void* d_ws, size_t ws_size,
                              hipStream_t stream) {
  (void)in_sizes; (void)n_in; (void)out_size; (void)ws_size;
  const float* x  = (const float*)d_in[0];
  const float* Wq = (const float*)d_in[1];
  const float* bq = (const float*)d_in[2];
  const float* Wk = (const float*)d_in[3];
  const float* bk = (const float*)d_in[4];
  const float* Wv = (const float*)d_in[5];
  const float* bv = (const float*)d_in[6];
  float* out = (float*)d_out;

  ushort* qws = (ushort*)d_ws;                       // bf16 q: 4 MB
  ushort* kws = qws + (size_t)NB * SS * DD;          // bf16 k: 4 MB
  ushort* vws = kws + (size_t)NB * SS * DD;          // bf16 v^T: 4 MB
  float* pws = (float*)(vws + (size_t)NB * SS * DD); // partials: ~34 MB

  proj_kernel<<<dim3(NB * SS / 64), dim3(256), 0, stream>>>(
      x, Wq, bq, Wk, bk, Wv, bv, qws, kws, vws);
  attn_part<<<dim3(NB * 160), dim3(256), 0, stream>>>(
      qws, kws, vws, pws);
  combine_kernel<<<dim3(NB * 64), dim3(256), 0, stream>>>(pws, out);
}

// Round 7
// 132.408 us; speedup vs baseline: 1.0287x; 1.0287x over previous
//
#include <hip/hip_runtime.h>
#include <hip/hip_bf16.h>

#define NB 16
#define SS 2048
#define DD 64

typedef __attribute__((ext_vector_type(8))) short short8;
typedef __attribute__((ext_vector_type(4))) float f32x4;

// SCALE * log2(e), folded so softmax exp is one v_mul + one v_exp
#define SCL2E 0.18033688011112042f

// partial slot: 32x64 acc + 32 l, padded
#define PSLOT 2080

// round-to-nearest-even f32 -> bf16 (as raw short)
__device__ __forceinline__ short f2bf(float f) {
  union { float f; unsigned u; } v; v.f = f;
  unsigned r = (v.u + 0x7fffu + ((v.u >> 16) & 1u)) >> 16;
  return (short)r;
}

__device__ __forceinline__ short8 load_a_frag_f32(const float* p) {
  float4 u = *(const float4*)p;
  float4 w = *(const float4*)(p + 4);
  short8 r;
  r[0] = f2bf(u.x); r[1] = f2bf(u.y); r[2] = f2bf(u.z); r[3] = f2bf(u.w);
  r[4] = f2bf(w.x); r[5] = f2bf(w.y); r[6] = f2bf(w.z); r[7] = f2bf(w.w);
  return r;
}

// ---------------------------------------------------------------------------
// QKV projection. Block = 4 waves = 64 seq rows. W bf16->LDS once per block.
// Q,K: MFMA C/D -> LDS tile -> coalesced row-major 16B stores.
// V: LDS transpose -> vT[b][d][s].
// ---------------------------------------------------------------------------
__global__ __launch_bounds__(256) void proj_kernel(
    const float* __restrict__ x,
    const float* __restrict__ Wq, const float* __restrict__ bq,
    const float* __restrict__ Wk, const float* __restrict__ bk,
    const float* __restrict__ Wv, const float* __restrict__ bv,
    ushort* __restrict__ qo, ushort* __restrict__ ko, ushort* __restrict__ vT)
{
  __shared__ __align__(16) ushort Wt[3][64][72];   // W^T[n][k], bf16
  __shared__ __align__(16) ushort Vs[64][72];      // staging tile
  const int t = threadIdx.x;
  {
    const float* Ws[3] = {Wq, Wk, Wv};
    for (int m = 0; m < 3; ++m)
      for (int i = 0; i < 4; ++i) {
        int idx = i * 1024 + t * 4;
        int kk = idx >> 6, n0 = idx & 63;
        float4 w4 = *(const float4*)(Ws[m] + kk * 64 + n0);
        Wt[m][n0 + 0][kk] = (ushort)f2bf(w4.x);
        Wt[m][n0 + 1][kk] = (ushort)f2bf(w4.y);
        Wt[m][n0 + 2][kk] = (ushort)f2bf(w4.z);
        Wt[m][n0 + 3][kk] = (ushort)f2bf(w4.w);
      }
  }
  __syncthreads();

  const int lane = t & 63, w = t >> 6;
  const int l15 = lane & 15, quad = lane >> 4;
  const int g = blockIdx.x * 64 + w * 16 + l15;
  short8 a0 = load_a_frag_f32(x + (size_t)g * 64 + quad * 8);
  short8 a1 = load_a_frag_f32(x + (size_t)g * 64 + 32 + quad * 8);
  const int lrow0 = w * 16 + quad * 4;

  for (int m = 0; m < 3; ++m) {
    const float* bp = (m == 0 ? bq : (m == 1 ? bk : bv));
#pragma unroll
    for (int nt = 0; nt < 4; ++nt) {
      short8 b0 = *(const short8*)&Wt[m][nt * 16 + l15][quad * 8];
      short8 b1 = *(const short8*)&Wt[m][nt * 16 + l15][32 + quad * 8];
      f32x4 acc = {0.f, 0.f, 0.f, 0.f};
      acc = __builtin_amdgcn_mfma_f32_16x16x32_bf16(a0, b0, acc, 0, 0, 0);
      acc = __builtin_amdgcn_mfma_f32_16x16x32_bf16(a1, b1, acc, 0, 0, 0);
      float bb = bp[nt * 16 + l15];
#pragma unroll
      for (int r = 0; r < 4; ++r)
        Vs[lrow0 + r][nt * 16 + l15] = (ushort)f2bf(acc[r] + bb);
    }
    __syncthreads();
    if (m < 2) {
      ushort* outp = (m == 0 ? qo : ko);
      const int row = t >> 2, col0 = (t & 3) * 16;
      int4 d0 = *(const int4*)&Vs[row][col0];
      int4 d1 = *(const int4*)&Vs[row][col0 + 8];
      ushort* dst = outp + (size_t)(blockIdx.x * 64 + row) * 64 + col0;
      ((int4*)dst)[0] = d0;
      ((int4*)dst)[1] = d1;
    } else {
      const int batch = blockIdx.x >> 5;
      const int s0 = (blockIdx.x & 31) * 64;
      const int d = t >> 2, j0 = (t & 3) * 16;
      ushort tmp[16];
      for (int j = 0; j < 16; ++j) tmp[j] = Vs[j0 + j][d];
      ushort* dst = vT + (size_t)batch * DD * SS + (size_t)d * SS + s0 + j0;
      ((int4*)dst)[0] = ((int4*)tmp)[0];
      ((int4*)dst)[1] = ((int4*)tmp)[1];
    }
    if (m < 2) __syncthreads();
  }
}

// ---------------------------------------------------------------------------
// exp + packed P write + PV for one 16-query half. Key interleave: c[ct] at
// lane l15 is key kb + 4*l15 + ct -> lane's 4 P-values are adjacent cols ->
// 2x v_cvt_pk_bf16_f32 + one ds_write_b64 per row. MASKED compile-time.
// ---------------------------------------------------------------------------
template<bool MASKED>
__device__ __forceinline__ void attn_half(
    const f32x4 (&c)[4], float (&l_part)[4], f32x4 (&acc)[4],
    const short8 (&vf0)[4], const short8 (&vf1)[4],
    ushort* __restrict__ Pw, int kb4, int rowb, int l15, int quad)
{
#pragma unroll
  for (int r = 0; r < 4; ++r) {
    float pe[4];
#pragma unroll
    for (int ct = 0; ct < 4; ++ct) {
      pe[ct] = __builtin_amdgcn_exp2f(c[ct][r] * SCL2E);
      if (MASKED && (kb4 + ct > rowb + r)) pe[ct] = 0.f;
    }
    l_part[r] += (pe[0] + pe[1]) + (pe[2] + pe[3]);
    __hip_bfloat162 h01 = __float22bfloat162_rn(make_float2(pe[0], pe[1]));
    __hip_bfloat162 h23 = __float22bfloat162_rn(make_float2(pe[2], pe[3]));
    uint2 pwv;
    pwv.x = *reinterpret_cast<unsigned*>(&h01);
    pwv.y = *reinterpret_cast<unsigned*>(&h23);
    *(uint2*)&Pw[(quad * 4 + r) * 72 + 4 * l15] = pwv;
  }
  short8 pa0 = *(const short8*)&Pw[l15 * 72 + quad * 8];
  short8 pa1 = *(const short8*)&Pw[l15 * 72 + 32 + quad * 8];
#pragma unroll
  for (int nt = 0; nt < 4; ++nt) {
    acc[nt] = __builtin_amdgcn_mfma_f32_16x16x32_bf16(pa0, vf0[nt], acc[nt], 0, 0, 0);
    acc[nt] = __builtin_amdgcn_mfma_f32_16x16x32_bf16(pa1, vf1[nt], acc[nt], 0, 0, 0);
  }
}

// ---------------------------------------------------------------------------
// Wave-independent chunked flash attention. Each WAVE owns one item
// (batch, 32-query tile, <=8x64-key chunk); no cross-wave coupling, no
// barriers, LDS = per-wave P buffer only -> whole grid (640 blocks) is
// co-resident. Single-chunk items finalize straight to out; multi-chunk
// items write unnormalized partials (no-max softmax => plain sums).
// ---------------------------------------------------------------------------
__global__ __launch_bounds__(256, 3) void attn_part(
    const ushort* __restrict__ qg, const ushort* __restrict__ kg,
    const ushort* __restrict__ vT, float* __restrict__ pws,
    float* __restrict__ out)
{
  __shared__ __align__(16) ushort P_lds[4][16 * 72];  // 9216 B total

  const int t = threadIdx.x, bid = blockIdx.x;
  const int w = t >> 6, lane = t & 63;
  const int l15 = lane & 15, quad = lane >> 4;
  const int batch = bid & 15;                 // 2 batches per XCD (bid%8)
  const int u = (bid >> 4) * 4 + w;           // wave item id, 0..159

  int qt, c;
  if (u < 16)      { qt = u;               c = 0; }
  else if (u < 48) { int v = u - 16; qt = 16 + (v >> 1); c = v & 1; }
  else if (u < 96) { int v = u - 48; int q3 = v / 3; qt = 32 + q3; c = v - 3 * q3; }
  else             { int v = u - 96; qt = 48 + (v >> 2); c = v & 3; }

  const int q0 = qt * 32;
  const int nkt = (qt >> 1) + 1;              // 64-key tiles for this qt
  const int t0 = 8 * c;
  const int tend = min(t0 + 8, nkt);
  const size_t bbase = (size_t)batch * SS * DD;
  ushort* Pw = &P_lds[w][0];

  // A-frags for both q-halves
  const ushort* qp = qg + bbase + (size_t)(q0 + l15) * 64 + quad * 8;
  short8 a0 = *(const short8*)qp;
  short8 a1 = *(const short8*)(qp + 32);
  short8 a2 = *(const short8*)(qp + 16 * 64);
  short8 a3 = *(const short8*)(qp + 16 * 64 + 32);

  f32x4 acc0[4], acc1[4];
  float l0[4] = {0.f, 0.f, 0.f, 0.f}, l1[4] = {0.f, 0.f, 0.f, 0.f};
#pragma unroll
  for (int nt = 0; nt < 4; ++nt) {
    acc0[nt] = (f32x4){0.f, 0.f, 0.f, 0.f};
    acc1[nt] = (f32x4){0.f, 0.f, 0.f, 0.f};
  }

  // K with key interleave: frag ct, lane l15 -> key 4*l15 + ct
  const ushort* kpc = kg + bbase + (size_t)(4 * l15) * 64 + quad * 8
                    + (size_t)t0 * 4096;
  const ushort* vp0 = vT + bbase + (size_t)l15 * SS + t0 * 64 + quad * 8;
  const ushort* vp1 = vp0 + 16 * SS;
  const ushort* vp2 = vp0 + 32 * SS;
  const ushort* vp3 = vp0 + 48 * SS;

  // preload first K tile
  short8 kc0[4], kc1[4];
#pragma unroll
  for (int ct = 0; ct < 4; ++ct) {
    kc0[ct] = *(const short8*)(kpc + ct * 64);
    kc1[ct] = *(const short8*)(kpc + ct * 64 + 32);
  }

  // unmasked iterations; if this chunk contains the diagonal tile, leave it
  // for the masked tail (which consumes the last prefetch).
  const int kend_nm = (tend == nkt) ? (nkt - 1) : tend;

  for (int kt = t0; kt < kend_nm; ++kt) {
    short8 vf0[4], vf1[4];
    vf0[0] = *(const short8*)(vp0); vf1[0] = *(const short8*)(vp0 + 32);
    vf0[1] = *(const short8*)(vp1); vf1[1] = *(const short8*)(vp1 + 32);
    vf0[2] = *(const short8*)(vp2); vf1[2] = *(const short8*)(vp2 + 32);
    vf0[3] = *(const short8*)(vp3); vf1[3] = *(const short8*)(vp3 + 32);

    // prefetch next K tile (tile index <= nkt-1 <= 31: always in-bounds)
    short8 kn0[4], kn1[4];
#pragma unroll
    for (int ct = 0; ct < 4; ++ct) {
      kn0[ct] = *(const short8*)(kpc + 4096 + ct * 64);
      kn1[ct] = *(const short8*)(kpc + 4096 + ct * 64 + 32);
    }

    f32x4 c0[4], c1[4];
#pragma unroll
    for (int ct = 0; ct < 4; ++ct) {
      c0[ct] = (f32x4){0.f, 0.f, 0.f, 0.f};
      c0[ct] = __builtin_amdgcn_mfma_f32_16x16x32_bf16(a0, kc0[ct], c0[ct], 0, 0, 0);
      c0[ct] = __builtin_amdgcn_mfma_f32_16x16x32_bf16(a1, kc1[ct], c0[ct], 0, 0, 0);
      c1[ct] = (f32x4){0.f, 0.f, 0.f, 0.f};
      c1[ct] = __builtin_amdgcn_mfma_f32_16x16x32_bf16(a2, kc0[ct], c1[ct], 0, 0, 0);
      c1[ct] = __builtin_amdgcn_mfma_f32_16x16x32_bf16(a3, kc1[ct], c1[ct], 0, 0, 0);
    }

    const int kb4 = kt * 64 + 4 * l15;
    attn_half<false>(c0, l0, acc0, vf0, vf1, Pw, kb4, q0 + quad * 4, l15, quad);
    attn_half<false>(c1, l1, acc1, vf0, vf1, Pw, kb4, q0 + 16 + quad * 4, l15, quad);

#pragma unroll
    for (int ct = 0; ct < 4; ++ct) { kc0[ct] = kn0[ct]; kc1[ct] = kn1[ct]; }
    kpc += 4096;
    vp0 += 64; vp1 += 64; vp2 += 64; vp3 += 64;
  }

  if (tend == nkt) {   // masked diagonal tile, kt = nkt-1 (kc holds its frags)
    short8 vf0[4], vf1[4];
    vf0[0] = *(const short8*)(vp0); vf1[0] = *(const short8*)(vp0 + 32);
    vf0[1] = *(const short8*)(vp1); vf1[1] = *(const short8*)(vp1 + 32);
    vf0[2] = *(const short8*)(vp2); vf1[2] = *(const short8*)(vp2 + 32);
    vf0[3] = *(const short8*)(vp3); vf1[3] = *(const short8*)(vp3 + 32);

    f32x4 c0[4], c1[4];
#pragma unroll
    for (int ct = 0; ct < 4; ++ct) {
      c0[ct] = (f32x4){0.f, 0.f, 0.f, 0.f};
      c0[ct] = __builtin_amdgcn_mfma_f32_16x16x32_bf16(a0, kc0[ct], c0[ct], 0, 0, 0);
      c0[ct] = __builtin_amdgcn_mfma_f32_16x16x32_bf16(a1, kc1[ct], c0[ct], 0, 0, 0);
      c1[ct] = (f32x4){0.f, 0.f, 0.f, 0.f};
      c1[ct] = __builtin_amdgcn_mfma_f32_16x16x32_bf16(a2, kc0[ct], c1[ct], 0, 0, 0);
      c1[ct] = __builtin_amdgcn_mfma_f32_16x16x32_bf16(a3, kc1[ct], c1[ct], 0, 0, 0);
    }
    const int kb4 = (nkt - 1) * 64 + 4 * l15;
    attn_half<true>(c0, l0, acc0, vf0, vf1, Pw, kb4, q0 + quad * 4, l15, quad);
    attn_half<true>(c1, l1, acc1, vf0, vf1, Pw, kb4, q0 + 16 + quad * 4, l15, quad);
  }

  // reduce l over the 16-lane row groups (once per wave)
#pragma unroll
  for (int r = 0; r < 4; ++r)
    for (int off = 1; off < 16; off <<= 1) {
      l0[r] += __shfl_xor(l0[r], off, 64);
      l1[r] += __shfl_xor(l1[r], off, 64);
    }

  if (c == 0 && tend == nkt) {
    // single-chunk item: normalize and write final output directly
    float iv0[4], iv1[4];
#pragma unroll
    for (int r = 0; r < 4; ++r) { iv0[r] = 1.0f / l0[r]; iv1[r] = 1.0f / l1[r]; }
    float* ob = out + bbase;
#pragma unroll
    for (int r = 0; r < 4; ++r)
#pragma unroll
      for (int nt = 0; nt < 4; ++nt) {
        ob[(size_t)(q0 + quad * 4 + r) * 64 + nt * 16 + l15] = acc0[nt][r] * iv0[r];
        ob[(size_t)(q0 + 16 + quad * 4 + r) * 64 + nt * 16 + l15] = acc1[nt][r] * iv1[r];
      }
  } else {
    // multi-chunk item: write unnormalized partial + row sums
    float* ps = pws + (size_t)(((batch << 6) + qt) * 4 + c) * PSLOT;
#pragma unroll
    for (int r = 0; r < 4; ++r)
#pragma unroll
      for (int nt = 0; nt < 4; ++nt) {
        ps[(quad * 4 + r) * 64 + nt * 16 + l15] = acc0[nt][r];
        ps[(16 + quad * 4 + r) * 64 + nt * 16 + l15] = acc1[nt][r];
      }
    if (l15 == 0)
#pragma unroll
      for (int r = 0; r < 4; ++r) {
        ps[2048 + quad * 4 + r] = l0[r];
        ps[2048 + 16 + quad * 4 + r] = l1[r];
      }
  }
}

// ---------------------------------------------------------------------------
// Combine: block = (batch, qt in 16..63). Sum 2..4 partials, normalize, store.
// ---------------------------------------------------------------------------
__global__ __launch_bounds__(256) void combine_kernel(
    const float* __restrict__ pws, float* __restrict__ out)
{
  __shared__ float inv_s[32];
  const int t = threadIdx.x, bid = blockIdx.x;
  const int batch = bid & 15, qt = 16 + (bid >> 4);
  const int q0 = qt * 32;
  const int nkt = (qt >> 1) + 1;
  const int nch = (nkt + 7) >> 3;
  const float* ps0 = pws + (size_t)(((batch << 6) + qt) * 4) * PSLOT;

  if (t < 32) {
    float d = 0.f;
    for (int c = 0; c < nch; ++c) d += ps0[c * PSLOT + 2048 + t];
    inv_s[t] = 1.0f / d;
  }
  __syncthreads();

  const int row = t >> 3, col0 = (t & 7) * 8;
  float4 oa = {0.f, 0.f, 0.f, 0.f}, ob = {0.f, 0.f, 0.f, 0.f};
  for (int c = 0; c < nch; ++c) {
    float4 x0 = *(const float4*)(ps0 + c * PSLOT + row * 64 + col0);
    float4 x1 = *(const float4*)(ps0 + c * PSLOT + row * 64 + col0 + 4);
    oa.x += x0.x; oa.y += x0.y; oa.z += x0.z; oa.w += x0.w;
    ob.x += x1.x; ob.y += x1.y; ob.z += x1.z; ob.w += x1.w;
  }
  float iv = inv_s[row];
  oa.x *= iv; oa.y *= iv; oa.z *= iv; oa.w *= iv;
  ob.x *= iv; ob.y *= iv; ob.z *= iv; ob.w *= iv;
  float* op = out + (size_t)batch * SS * DD + (size_t)(q0 + row) * 64 + col0;
  *(float4*)op = oa;
  *(float4*)(op + 4) = ob;
}

extern "C" void kernel_launch(void* const* d_in, const int* in_sizes, int n_in,
                              void* d_out, int out_size, void* d_ws, size_t ws_size,
                              hipStream_t stream) {
  (void)in_sizes; (void)n_in; (void)out_size; (void)ws_size;
  const float* x  = (const float*)d_in[0];
  const float* Wq = (const float*)d_in[1];
  const float* bq = (const float*)d_in[2];
  const float* Wk = (const float*)d_in[3];
  const float* bk = (const float*)d_in[4];
  const float* Wv = (const float*)d_in[5];
  const float* bv = (const float*)d_in[6];
  float* out = (float*)d_out;

  ushort* qws = (ushort*)d_ws;                       // bf16 q: 4 MB
  ushort* kws = qws + (size_t)NB * SS * DD;          // bf16 k: 4 MB
  ushort* vws = kws + (size_t)NB * SS * DD;          // bf16 v^T: 4 MB
  float* pws = (float*)(vws + (size_t)NB * SS * DD); // partials: ~34 MB

  proj_kernel<<<dim3(NB * SS / 64), dim3(256), 0, stream>>>(
      x, Wq, bq, Wk, bk, Wv, bv, qws, kws, vws);
  attn_part<<<dim3(640), dim3(256), 0, stream>>>(
      qws, kws, vws, pws, out);
  combine_kernel<<<dim3(16 * 48), dim3(256), 0, stream>>>(pws, out);
}

// Round 8
// 128.488 us; speedup vs baseline: 1.0601x; 1.0305x over previous
//
#include <hip/hip_runtime.h>
#include <hip/hip_bf16.h>

#define NB 16
#define SS 2048
#define DD 64

typedef __attribute__((ext_vector_type(8))) short short8;
typedef __attribute__((ext_vector_type(4))) float f32x4;

// SCALE * log2(e), folded so softmax exp is one v_mul + one v_exp
#define SCL2E 0.18033688011112042f

// partial slot: 64x64 acc + 64 l, padded
#define PSLOT 4224

// round-to-nearest-even f32 -> bf16 (as raw short)
__device__ __forceinline__ short f2bf(float f) {
  union { float f; unsigned u; } v; v.f = f;
  unsigned r = (v.u + 0x7fffu + ((v.u >> 16) & 1u)) >> 16;
  return (short)r;
}

__device__ __forceinline__ short8 load_a_frag_f32(const float* p) {
  float4 u = *(const float4*)p;
  float4 w = *(const float4*)(p + 4);
  short8 r;
  r[0] = f2bf(u.x); r[1] = f2bf(u.y); r[2] = f2bf(u.z); r[3] = f2bf(u.w);
  r[4] = f2bf(w.x); r[5] = f2bf(w.y); r[6] = f2bf(w.z); r[7] = f2bf(w.w);
  return r;
}

// ---------------------------------------------------------------------------
// QKV projection (unchanged from R7).
// ---------------------------------------------------------------------------
__global__ __launch_bounds__(256) void proj_kernel(
    const float* __restrict__ x,
    const float* __restrict__ Wq, const float* __restrict__ bq,
    const float* __restrict__ Wk, const float* __restrict__ bk,
    const float* __restrict__ Wv, const float* __restrict__ bv,
    ushort* __restrict__ qo, ushort* __restrict__ ko, ushort* __restrict__ vT)
{
  __shared__ __align__(16) ushort Wt[3][64][72];
  __shared__ __align__(16) ushort Vs[64][72];
  const int t = threadIdx.x;
  {
    const float* Ws[3] = {Wq, Wk, Wv};
    for (int m = 0; m < 3; ++m)
      for (int i = 0; i < 4; ++i) {
        int idx = i * 1024 + t * 4;
        int kk = idx >> 6, n0 = idx & 63;
        float4 w4 = *(const float4*)(Ws[m] + kk * 64 + n0);
        Wt[m][n0 + 0][kk] = (ushort)f2bf(w4.x);
        Wt[m][n0 + 1][kk] = (ushort)f2bf(w4.y);
        Wt[m][n0 + 2][kk] = (ushort)f2bf(w4.z);
        Wt[m][n0 + 3][kk] = (ushort)f2bf(w4.w);
      }
  }
  __syncthreads();

  const int lane = t & 63, w = t >> 6;
  const int l15 = lane & 15, quad = lane >> 4;
  const int g = blockIdx.x * 64 + w * 16 + l15;
  short8 a0 = load_a_frag_f32(x + (size_t)g * 64 + quad * 8);
  short8 a1 = load_a_frag_f32(x + (size_t)g * 64 + 32 + quad * 8);
  const int lrow0 = w * 16 + quad * 4;

  for (int m = 0; m < 3; ++m) {
    const float* bp = (m == 0 ? bq : (m == 1 ? bk : bv));
#pragma unroll
    for (int nt = 0; nt < 4; ++nt) {
      short8 b0 = *(const short8*)&Wt[m][nt * 16 + l15][quad * 8];
      short8 b1 = *(const short8*)&Wt[m][nt * 16 + l15][32 + quad * 8];
      f32x4 acc = {0.f, 0.f, 0.f, 0.f};
      acc = __builtin_amdgcn_mfma_f32_16x16x32_bf16(a0, b0, acc, 0, 0, 0);
      acc = __builtin_amdgcn_mfma_f32_16x16x32_bf16(a1, b1, acc, 0, 0, 0);
      float bb = bp[nt * 16 + l15];
#pragma unroll
      for (int r = 0; r < 4; ++r)
        Vs[lrow0 + r][nt * 16 + l15] = (ushort)f2bf(acc[r] + bb);
    }
    __syncthreads();
    if (m < 2) {
      ushort* outp = (m == 0 ? qo : ko);
      const int row = t >> 2, col0 = (t & 3) * 16;
      int4 d0 = *(const int4*)&Vs[row][col0];
      int4 d1 = *(const int4*)&Vs[row][col0 + 8];
      ushort* dst = outp + (size_t)(blockIdx.x * 64 + row) * 64 + col0;
      ((int4*)dst)[0] = d0;
      ((int4*)dst)[1] = d1;
    } else {
      const int batch = blockIdx.x >> 5;
      const int s0 = (blockIdx.x & 31) * 64;
      const int d = t >> 2, j0 = (t & 3) * 16;
      ushort tmp[16];
      for (int j = 0; j < 16; ++j) tmp[j] = Vs[j0 + j][d];
      ushort* dst = vT + (size_t)batch * DD * SS + (size_t)d * SS + s0 + j0;
      ((int4*)dst)[0] = ((int4*)tmp)[0];
      ((int4*)dst)[1] = ((int4*)tmp)[1];
    }
    if (m < 2) __syncthreads();
  }
}

// ---------------------------------------------------------------------------
// exp + packed P write + PV for one 16-query group. Key interleave: c[ct] at
// lane l15 is key kb + 4*l15 + ct. MASKED compile-time.
// ---------------------------------------------------------------------------
template<bool MASKED>
__device__ __forceinline__ void attn_half(
    const f32x4 (&c)[4], float (&l_part)[4], f32x4 (&acc)[4],
    const short8 (&vf0)[4], const short8 (&vf1)[4],
    ushort* __restrict__ Pw, int kb4, int rowb, int l15, int quad)
{
#pragma unroll
  for (int r = 0; r < 4; ++r) {
    float pe[4];
#pragma unroll
    for (int ct = 0; ct < 4; ++ct) {
      pe[ct] = __builtin_amdgcn_exp2f(c[ct][r] * SCL2E);
      if (MASKED && (kb4 + ct > rowb + r)) pe[ct] = 0.f;
    }
    l_part[r] += (pe[0] + pe[1]) + (pe[2] + pe[3]);
    __hip_bfloat162 h01 = __float22bfloat162_rn(make_float2(pe[0], pe[1]));
    __hip_bfloat162 h23 = __float22bfloat162_rn(make_float2(pe[2], pe[3]));
    uint2 pwv;
    pwv.x = *reinterpret_cast<unsigned*>(&h01);
    pwv.y = *reinterpret_cast<unsigned*>(&h23);
    *(uint2*)&Pw[(quad * 4 + r) * 72 + 4 * l15] = pwv;
  }
  short8 pa0 = *(const short8*)&Pw[l15 * 72 + quad * 8];
  short8 pa1 = *(const short8*)&Pw[l15 * 72 + 32 + quad * 8];
#pragma unroll
  for (int nt = 0; nt < 4; ++nt) {
    acc[nt] = __builtin_amdgcn_mfma_f32_16x16x32_bf16(pa0, vf0[nt], acc[nt], 0, 0, 0);
    acc[nt] = __builtin_amdgcn_mfma_f32_16x16x32_bf16(pa1, vf1[nt], acc[nt], 0, 0, 0);
  }
}

// ---------------------------------------------------------------------------
// Wave-independent flash attention, 64 QUERIES per wave (K/V L1 bytes
// amortized 2x vs 32q). Item = (batch, 64q-tile qt, chunk c of <=4 key
// tiles). Grid 1024 blocks x 4 waves; waves with t0>=nkt exit. No barriers.
// ---------------------------------------------------------------------------
__global__ __launch_bounds__(256, 2) void attn_part(
    const ushort* __restrict__ qg, const ushort* __restrict__ kg,
    const ushort* __restrict__ vT, float* __restrict__ pws,
    float* __restrict__ out)
{
  __shared__ __align__(16) ushort P_lds[4][16 * 72];

  const int t = threadIdx.x, bid = blockIdx.x;
  const int w = t >> 6, lane = t & 63;
  const int l15 = lane & 15, quad = lane >> 4;
  const int batch = bid & 15;                 // bid%8 = XCD; batch pinned
  const int id = (bid >> 4) * 4 + w;          // 0..255
  const int qt = id >> 3;                     // 64q tile, 0..31
  const int c = id & 7;                       // chunk
  const int nkt = qt + 1;                     // 64-key tiles for this qt
  const int t0 = 4 * c;
  if (t0 >= nkt) return;                      // zombie wave (uniform, no barriers)
  const int tend = min(t0 + 4, nkt);

  const int q0 = qt * 64;
  const size_t bbase = (size_t)batch * SS * DD;
  ushort* Pw = &P_lds[w][0];

  // A-frags: 4 groups of 16 queries
  short8 a0[4], a1[4];
#pragma unroll
  for (int g = 0; g < 4; ++g) {
    const ushort* qp = qg + bbase + (size_t)(q0 + g * 16 + l15) * 64 + quad * 8;
    a0[g] = *(const short8*)qp;
    a1[g] = *(const short8*)(qp + 32);
  }

  f32x4 acc[4][4];
  float lp[4][4];
#pragma unroll
  for (int g = 0; g < 4; ++g)
#pragma unroll
    for (int nt = 0; nt < 4; ++nt) {
      acc[g][nt] = (f32x4){0.f, 0.f, 0.f, 0.f};
      lp[g][nt] = 0.f;
    }

  // K with key interleave: frag ct, lane l15 -> key 4*l15 + ct
  const ushort* kpc = kg + bbase + (size_t)(4 * l15) * 64 + quad * 8
                    + (size_t)t0 * 4096;
  const ushort* vp0 = vT + bbase + (size_t)l15 * SS + t0 * 64 + quad * 8;
  const ushort* vp1 = vp0 + 16 * SS;
  const ushort* vp2 = vp0 + 32 * SS;
  const ushort* vp3 = vp0 + 48 * SS;

  short8 kc0[4], kc1[4];
#pragma unroll
  for (int ct = 0; ct < 4; ++ct) {
    kc0[ct] = *(const short8*)(kpc + ct * 64);
    kc1[ct] = *(const short8*)(kpc + ct * 64 + 32);
  }

  const int kend_nm = (tend == nkt) ? (nkt - 1) : tend;

  for (int kt = t0; kt < kend_nm; ++kt) {
    short8 vf0[4], vf1[4];
    vf0[0] = *(const short8*)(vp0); vf1[0] = *(const short8*)(vp0 + 32);
    vf0[1] = *(const short8*)(vp1); vf1[1] = *(const short8*)(vp1 + 32);
    vf0[2] = *(const short8*)(vp2); vf1[2] = *(const short8*)(vp2 + 32);
    vf0[3] = *(const short8*)(vp3); vf1[3] = *(const short8*)(vp3 + 32);

    short8 kn0[4], kn1[4];
#pragma unroll
    for (int ct = 0; ct < 4; ++ct) {
      kn0[ct] = *(const short8*)(kpc + 4096 + ct * 64);
      kn1[ct] = *(const short8*)(kpc + 4096 + ct * 64 + 32);
    }

    const int kb4 = kt * 64 + 4 * l15;
#pragma unroll
    for (int g = 0; g < 4; ++g) {
      f32x4 cc[4];
#pragma unroll
      for (int ct = 0; ct < 4; ++ct) {
        cc[ct] = (f32x4){0.f, 0.f, 0.f, 0.f};
        cc[ct] = __builtin_amdgcn_mfma_f32_16x16x32_bf16(a0[g], kc0[ct], cc[ct], 0, 0, 0);
        cc[ct] = __builtin_amdgcn_mfma_f32_16x16x32_bf16(a1[g], kc1[ct], cc[ct], 0, 0, 0);
      }
      attn_half<false>(cc, lp[g], acc[g], vf0, vf1, Pw, kb4,
                       q0 + g * 16 + quad * 4, l15, quad);
    }

#pragma unroll
    for (int ct = 0; ct < 4; ++ct) { kc0[ct] = kn0[ct]; kc1[ct] = kn1[ct]; }
    kpc += 4096;
    vp0 += 64; vp1 += 64; vp2 += 64; vp3 += 64;
  }

  if (tend == nkt) {   // masked diagonal tile (kc holds its frags)
    short8 vf0[4], vf1[4];
    vf0[0] = *(const short8*)(vp0); vf1[0] = *(const short8*)(vp0 + 32);
    vf0[1] = *(const short8*)(vp1); vf1[1] = *(const short8*)(vp1 + 32);
    vf0[2] = *(const short8*)(vp2); vf1[2] = *(const short8*)(vp2 + 32);
    vf0[3] = *(const short8*)(vp3); vf1[3] = *(const short8*)(vp3 + 32);

    const int kb4 = (nkt - 1) * 64 + 4 * l15;
#pragma unroll
    for (int g = 0; g < 4; ++g) {
      f32x4 cc[4];
#pragma unroll
      for (int ct = 0; ct < 4; ++ct) {
        cc[ct] = (f32x4){0.f, 0.f, 0.f, 0.f};
        cc[ct] = __builtin_amdgcn_mfma_f32_16x16x32_bf16(a0[g], kc0[ct], cc[ct], 0, 0, 0);
        cc[ct] = __builtin_amdgcn_mfma_f32_16x16x32_bf16(a1[g], kc1[ct], cc[ct], 0, 0, 0);
      }
      attn_half<true>(cc, lp[g], acc[g], vf0, vf1, Pw, kb4,
                      q0 + g * 16 + quad * 4, l15, quad);
    }
  }

  // reduce l over the 16-lane row groups
#pragma unroll
  for (int g = 0; g < 4; ++g)
#pragma unroll
    for (int r = 0; r < 4; ++r)
      for (int off = 1; off < 16; off <<= 1)
        lp[g][r] += __shfl_xor(lp[g][r], off, 64);

  if (nkt <= 4) {
    // single-chunk item: finalize straight to out
    float* ob = out + bbase;
#pragma unroll
    for (int g = 0; g < 4; ++g) {
      float iv[4];
#pragma unroll
      for (int r = 0; r < 4; ++r) iv[r] = 1.0f / lp[g][r];
#pragma unroll
      for (int r = 0; r < 4; ++r)
#pragma unroll
        for (int nt = 0; nt < 4; ++nt)
          ob[(size_t)(q0 + g * 16 + quad * 4 + r) * 64 + nt * 16 + l15] =
              acc[g][nt][r] * iv[r];
    }
  } else {
    // write unnormalized partial + row sums
    float* ps = pws + (size_t)(((batch << 5) + qt) * 8 + c) * PSLOT;
#pragma unroll
    for (int g = 0; g < 4; ++g) {
#pragma unroll
      for (int r = 0; r < 4; ++r)
#pragma unroll
        for (int nt = 0; nt < 4; ++nt)
          ps[(g * 16 + quad * 4 + r) * 64 + nt * 16 + l15] = acc[g][nt][r];
      if (l15 == 0)
#pragma unroll
        for (int r = 0; r < 4; ++r)
          ps[4096 + g * 16 + quad * 4 + r] = lp[g][r];
    }
  }
}

// ---------------------------------------------------------------------------
// Combine: block = (batch, qt in 4..31). Sum 2..8 partials, normalize, store.
// ---------------------------------------------------------------------------
__global__ __launch_bounds__(256) void combine_kernel(
    const float* __restrict__ pws, float* __restrict__ out)
{
  __shared__ float inv_s[64];
  const int t = threadIdx.x, bid = blockIdx.x;
  const int batch = bid & 15, qt = 4 + (bid >> 4);
  const int q0 = qt * 64;
  const int nch = (qt + 4) >> 2;              // ceil((qt+1)/4)
  const float* ps0 = pws + (size_t)(((batch << 5) + qt) * 8) * PSLOT;

  if (t < 64) {
    float d = 0.f;
    for (int c = 0; c < nch; ++c) d += ps0[c * PSLOT + 4096 + t];
    inv_s[t] = 1.0f / d;
  }
  __syncthreads();

  const int row = t >> 2, col0 = (t & 3) * 16;
  float4 o[4];
#pragma unroll
  for (int i = 0; i < 4; ++i) o[i] = (float4){0.f, 0.f, 0.f, 0.f};
  for (int c = 0; c < nch; ++c) {
    const float* pr = ps0 + c * PSLOT + row * 64 + col0;
#pragma unroll
    for (int i = 0; i < 4; ++i) {
      float4 xv = *(const float4*)(pr + i * 4);
      o[i].x += xv.x; o[i].y += xv.y; o[i].z += xv.z; o[i].w += xv.w;
    }
  }
  float iv = inv_s[row];
  float* op = out + (size_t)batch * SS * DD + (size_t)(q0 + row) * 64 + col0;
#pragma unroll
  for (int i = 0; i < 4; ++i) {
    o[i].x *= iv; o[i].y *= iv; o[i].z *= iv; o[i].w *= iv;
    *(float4*)(op + i * 4) = o[i];
  }
}

extern "C" void kernel_launch(void* const* d_in, const int* in_sizes, int n_in,
                              void* d_out, int out_size, void* d_ws, size_t ws_size,
                              hipStream_t stream) {
  (void)in_sizes; (void)n_in; (void)out_size; (void)ws_size;
  const float* x  = (const float*)d_in[0];
  const float* Wq = (const float*)d_in[1];
  const float* bq = (const float*)d_in[2];
  const float* Wk = (const float*)d_in[3];
  const float* bk = (const float*)d_in[4];
  const float* Wv = (const float*)d_in[5];
  const float* bv = (const float*)d_in[6];
  float* out = (float*)d_out;

  ushort* qws = (ushort*)d_ws;                       // bf16 q: 4 MB
  ushort* kws = qws + (size_t)NB * SS * DD;          // bf16 k: 4 MB
  ushort* vws = kws + (size_t)NB * SS * DD;          // bf16 v^T: 4 MB
  float* pws = (float*)(vws + (size_t)NB * SS * DD); // partials: ~69 MB

  proj_kernel<<<dim3(NB * SS / 64), dim3(256), 0, stream>>>(
      x, Wq, bq, Wk, bk, Wv, bv, qws, kws, vws);
  attn_part<<<dim3(1024), dim3(256), 0, stream>>>(
      qws, kws, vws, pws, out);
  combine_kernel<<<dim3(16 * 28), dim3(256), 0, stream>>>(pws, out);
}